// Round 2
// baseline (253.379 us; speedup 1.0000x reference)
//
#include <hip/hip_runtime.h>
#include <math.h>

// Problem constants
#define NBATCH   32768
#define OWN_DIM  7
#define INTR_DIM 5
#define N_HEADS  3
#define HEAD_DIM 5
#define N_INTR   256
#define ROWLEN   1287   // OWN_DIM + N_INTR*INTR_DIM
#define SMROW    1288   // padded
#define XDIM     22     // OWN_DIM + N_HEADS*HEAD_DIM
#define H1DIM    256
#define H2DIM    256

__device__ __forceinline__ float fast_tanhf(float x) {
    // tanh(x) = 1 - 2/(exp(2x)+1); exact at +-inf saturation, ~1e-7 abs error
    float e = __expf(2.0f * x);
    return 1.0f - 2.0f / (e + 1.0f);
}

__device__ __forceinline__ float leaky02(float x) {
    // leaky_relu slope 0.2: for x<0, 0.2x > x; for x>=0, x >= 0.2x
    return fmaxf(x, 0.2f * x);
}

// ---------------- Kernel A: attention + layernorm -> x (B x 22) ----------------
// one wave per sample, 4 samples per 256-thread block
__global__ __launch_bounds__(256) void attn_ln_kernel(
    const float* __restrict__ obs,
    const float* __restrict__ Wq, const float* __restrict__ bq,
    const float* __restrict__ Wk, const float* __restrict__ bk,
    const float* __restrict__ Wv, const float* __restrict__ bv,
    const float* __restrict__ v_att, const float* __restrict__ temp,
    const float* __restrict__ ln_g, const float* __restrict__ ln_b,
    float* __restrict__ xout)
{
    __shared__ float sm[4][SMROW];
    const int wid  = threadIdx.x >> 6;
    const int lane = threadIdx.x & 63;
    const int s    = blockIdx.x * 4 + wid;

    const float* row = obs + (size_t)s * ROWLEN;
    float* smr = sm[wid];
    for (int i = lane; i < ROWLEN; i += 64) smr[i] = row[i];
    __syncthreads();

    // q[h][d] (redundant per lane; own is broadcast from LDS)
    float q[N_HEADS][HEAD_DIM];
    #pragma unroll
    for (int h = 0; h < N_HEADS; ++h) {
        #pragma unroll
        for (int d = 0; d < HEAD_DIM; ++d) {
            float a = bq[h*HEAD_DIM + d];
            #pragma unroll
            for (int o = 0; o < OWN_DIM; ++o)
                a += smr[o] * Wq[h*OWN_DIM*HEAD_DIM + o*HEAD_DIM + d];
            q[h][d] = a;
        }
    }

    const float fac = fabsf(temp[0]) / 2.23606797749979f;  // |T| / sqrt(5)

    // each lane owns items n = lane + 64*r  (stride-5 LDS reads -> conflict free)
    float xi[4][INTR_DIM];   // keep intr values in regs for v recompute
    float sc[N_HEADS][4];
    #pragma unroll
    for (int r = 0; r < 4; ++r) {
        const int n = lane + 64*r;
        const float* it = smr + OWN_DIM + n*INTR_DIM;
        #pragma unroll
        for (int i = 0; i < INTR_DIM; ++i) xi[r][i] = it[i];
        float asum = fabsf(xi[r][0]) + fabsf(xi[r][1]) + fabsf(xi[r][2])
                   + fabsf(xi[r][3]) + fabsf(xi[r][4]);
        const bool pad = asum < 1e-6f;
        #pragma unroll
        for (int h = 0; h < N_HEADS; ++h) {
            float dot = 0.0f;
            #pragma unroll
            for (int d = 0; d < HEAD_DIM; ++d) {
                float kv = bk[h*HEAD_DIM + d];
                #pragma unroll
                for (int i = 0; i < INTR_DIM; ++i)
                    kv += xi[r][i] * Wk[h*INTR_DIM*HEAD_DIM + i*HEAD_DIM + d];
                dot += fast_tanhf(q[h][d] + kv) * v_att[h*HEAD_DIM + d];
            }
            sc[h][r] = pad ? -__builtin_inff() : dot * fac;
        }
    }

    // per-head softmax over 256 items (4 local + 64-lane butterfly)
    float alpha[N_HEADS][4];
    #pragma unroll
    for (int h = 0; h < N_HEADS; ++h) {
        float m = fmaxf(fmaxf(sc[h][0], sc[h][1]), fmaxf(sc[h][2], sc[h][3]));
        #pragma unroll
        for (int o = 1; o < 64; o <<= 1) m = fmaxf(m, __shfl_xor(m, o, 64));
        const bool dead = (m == -__builtin_inff());   // all padded -> alpha=0 (nan_to_num)
        float ssum = 0.0f;
        #pragma unroll
        for (int r = 0; r < 4; ++r) {
            float e = dead ? 0.0f : __expf(sc[h][r] - m);
            alpha[h][r] = e; ssum += e;
        }
        #pragma unroll
        for (int o = 1; o < 64; o <<= 1) ssum += __shfl_xor(ssum, o, 64);
        float rinv = ssum > 0.0f ? 1.0f / ssum : 0.0f;
        #pragma unroll
        for (int r = 0; r < 4; ++r) alpha[h][r] *= rinv;
    }

    // context: recompute v per item (cheaper than keeping 60 regs), weight by alpha
    float ctx[N_HEADS][HEAD_DIM] = {};
    #pragma unroll
    for (int r = 0; r < 4; ++r) {
        #pragma unroll
        for (int h = 0; h < N_HEADS; ++h) {
            float a = alpha[h][r];
            #pragma unroll
            for (int d = 0; d < HEAD_DIM; ++d) {
                float vv = bv[h*HEAD_DIM + d];
                #pragma unroll
                for (int i = 0; i < INTR_DIM; ++i)
                    vv += xi[r][i] * Wv[h*INTR_DIM*HEAD_DIM + i*HEAD_DIM + d];
                ctx[h][d] += a * vv;
            }
        }
    }
    // butterfly-reduce the 15 context values; all lanes end with totals
    #pragma unroll
    for (int h = 0; h < N_HEADS; ++h) {
        #pragma unroll
        for (int d = 0; d < HEAD_DIM; ++d) {
            float v = ctx[h][d];
            #pragma unroll
            for (int o = 1; o < 64; o <<= 1) v += __shfl_xor(v, o, 64);
            ctx[h][d] = v;
        }
    }

    // layernorm over x = [own(7), ctx(15)] computed redundantly per lane
    float xv7[OWN_DIM];
    #pragma unroll
    for (int o = 0; o < OWN_DIM; ++o) xv7[o] = smr[o];
    float sum = 0.0f;
    #pragma unroll
    for (int o = 0; o < OWN_DIM; ++o) sum += xv7[o];
    #pragma unroll
    for (int h = 0; h < N_HEADS; ++h)
        #pragma unroll
        for (int d = 0; d < HEAD_DIM; ++d) sum += ctx[h][d];
    const float mu = sum * (1.0f / 22.0f);
    float var = 0.0f;
    #pragma unroll
    for (int o = 0; o < OWN_DIM; ++o) { float dd = xv7[o] - mu; var += dd*dd; }
    #pragma unroll
    for (int h = 0; h < N_HEADS; ++h)
        #pragma unroll
        for (int d = 0; d < HEAD_DIM; ++d) { float dd = ctx[h][d] - mu; var += dd*dd; }
    var *= (1.0f / 22.0f);
    const float rs = rsqrtf(var + 1e-5f);

    // lane j < 22 writes element j (static cndmask select chain, coalesced store)
    float xv = xv7[0];
    #pragma unroll
    for (int o = 1; o < OWN_DIM; ++o) xv = (lane == o) ? xv7[o] : xv;
    #pragma unroll
    for (int j = 0; j < 15; ++j) xv = (lane == OWN_DIM + j) ? ctx[j/5][j%5] : xv;
    if (lane < XDIM) {
        xout[(size_t)s * XDIM + lane] = (xv - mu) * rs * ln_g[lane] + ln_b[lane];
    }
}

// ---------------- Kernel B: MLP 22->256->256->2 (+log_std) ----------------
// 32 samples per 256-thread block; thread owns 8 samples x 4 contiguous cols
__global__ __launch_bounds__(256) void mlp_kernel(
    const float* __restrict__ x,
    const float* __restrict__ W1, const float* __restrict__ b1,
    const float* __restrict__ W2, const float* __restrict__ b2,
    const float* __restrict__ Wf, const float* __restrict__ bf,
    const float* __restrict__ lstd, float* __restrict__ out)
{
    __shared__ __align__(16) float xs[32 * XDIM];       //  2.8 KB
    __shared__ __align__(16) float h1s[32 * H1DIM];     // 32 KB
    __shared__ __align__(16) float w2s[16 * H2DIM];     // 16 KB (K-chunk of W2)
    __shared__ __align__(16) float wfs[H2DIM * 2];      //  2 KB

    const int t   = threadIdx.x;
    const int blk = blockIdx.x;

    // stage x tile (contiguous 704 floats) + Wf (512 floats — strided, 256 thr!)
    for (int i = t; i < 32 * XDIM; i += 256) xs[i] = x[(size_t)blk * 32 * XDIM + i];
    for (int i = t; i < H2DIM * 2; i += 256) wfs[i] = Wf[i];

    // layer 1: thread t computes h1[:, t]; W1 column preloaded in regs
    float w1r[XDIM];
    #pragma unroll
    for (int i = 0; i < XDIM; ++i) w1r[i] = W1[i * H1DIM + t];
    const float b1t = b1[t];
    __syncthreads();
    for (int e = 0; e < 32; ++e) {
        float a = b1t;
        #pragma unroll
        for (int i = 0; i < XDIM; ++i) a += xs[e * XDIM + i] * w1r[i];
        h1s[e * H1DIM + t] = leaky02(a);
    }

    // layer 2: K-chunked; conflict-free (W2 reads lane-contiguous, h1 reads uniform)
    const int wid  = t >> 6;
    const int lane = t & 63;
    const int s0 = wid * 8;       // 8 samples per thread
    const int j0 = lane * 4;      // 4 contiguous cols per thread

    float4 b2v = *(const float4*)&b2[j0];
    float acc[8][4];
    #pragma unroll
    for (int si = 0; si < 8; ++si) {
        acc[si][0] = b2v.x; acc[si][1] = b2v.y; acc[si][2] = b2v.z; acc[si][3] = b2v.w;
    }

    for (int kc = 0; kc < 16; ++kc) {
        __syncthreads();   // protects h1s (first iter) and w2s reuse (later iters)
        #pragma unroll
        for (int i = 0; i < 16; ++i)
            w2s[i * H2DIM + t] = W2[(size_t)(kc * 16 + i) * H2DIM + t];
        __syncthreads();
        #pragma unroll
        for (int k = 0; k < 16; k += 4) {
            float4 h4[8];
            #pragma unroll
            for (int si = 0; si < 8; ++si)
                h4[si] = *(const float4*)&h1s[(s0 + si) * H1DIM + kc * 16 + k];
            #pragma unroll
            for (int dk = 0; dk < 4; ++dk) {
                float4 w = *(const float4*)&w2s[(k + dk) * H2DIM + j0];
                #pragma unroll
                for (int si = 0; si < 8; ++si) {
                    float hv = (dk == 0) ? h4[si].x : (dk == 1) ? h4[si].y
                             : (dk == 2) ? h4[si].z : h4[si].w;
                    acc[si][0] = fmaf(hv, w.x, acc[si][0]);
                    acc[si][1] = fmaf(hv, w.y, acc[si][1]);
                    acc[si][2] = fmaf(hv, w.z, acc[si][2]);
                    acc[si][3] = fmaf(hv, w.w, acc[si][3]);
                }
            }
        }
    }

    // layer 3: partial out per thread, wave-reduce over the 64 col-group lanes
    float p[8][2] = {};
    #pragma unroll
    for (int si = 0; si < 8; ++si) {
        #pragma unroll
        for (int jj = 0; jj < 4; ++jj) {
            float h2v = leaky02(acc[si][jj]);
            p[si][0] += h2v * wfs[(j0 + jj) * 2 + 0];
            p[si][1] += h2v * wfs[(j0 + jj) * 2 + 1];
        }
    }
    #pragma unroll
    for (int o = 1; o < 64; o <<= 1) {
        #pragma unroll
        for (int si = 0; si < 8; ++si) {
            p[si][0] += __shfl_xor(p[si][0], o, 64);
            p[si][1] += __shfl_xor(p[si][1], o, 64);
        }
    }
    if (lane == 0) {
        const float bf0 = bf[0], bf1 = bf[1];
        const float ls0 = lstd[0], ls1 = lstd[1];
        #pragma unroll
        for (int si = 0; si < 8; ++si) {
            const int srow = blk * 32 + s0 + si;
            float4 o4;
            o4.x = p[si][0] + bf0;
            o4.y = p[si][1] + bf1;
            o4.z = ls0;
            o4.w = ls1;
            *(float4*)&out[(size_t)srow * 4] = o4;
        }
    }
}

extern "C" void kernel_launch(void* const* d_in, const int* in_sizes, int n_in,
                              void* d_out, int out_size, void* d_ws, size_t ws_size,
                              hipStream_t stream) {
    const float* obs   = (const float*)d_in[0];
    const float* Wq    = (const float*)d_in[1];
    const float* bq    = (const float*)d_in[2];
    const float* Wk    = (const float*)d_in[3];
    const float* bk    = (const float*)d_in[4];
    const float* Wv    = (const float*)d_in[5];
    const float* bv    = (const float*)d_in[6];
    const float* v_att = (const float*)d_in[7];
    const float* temp  = (const float*)d_in[8];
    const float* ln_g  = (const float*)d_in[9];
    const float* ln_b  = (const float*)d_in[10];
    const float* W1    = (const float*)d_in[11];
    const float* b1    = (const float*)d_in[12];
    const float* W2    = (const float*)d_in[13];
    const float* b2    = (const float*)d_in[14];
    const float* Wf    = (const float*)d_in[15];
    const float* bf    = (const float*)d_in[16];
    const float* lstd  = (const float*)d_in[17];

    float* xbuf = (float*)d_ws;   // B x 22 normalized features (2.88 MB)
    float* outf = (float*)d_out;

    attn_ln_kernel<<<NBATCH / 4, 256, 0, stream>>>(
        obs, Wq, bq, Wk, bk, Wv, bv, v_att, temp, ln_g, ln_b, xbuf);
    mlp_kernel<<<NBATCH / 32, 256, 0, stream>>>(
        xbuf, W1, b1, W2, b2, Wf, bf, lstd, outf);
}

// Round 3
// 198.625 us; speedup vs baseline: 1.2757x; 1.2757x over previous
//
#include <hip/hip_runtime.h>
#include <math.h>

// Problem constants
#define NBATCH   32768
#define OWN_DIM  7
#define INTR_DIM 5
#define N_HEADS  3
#define HEAD_DIM 5
#define N_INTR   256
#define ROWLEN   1287   // OWN_DIM + N_INTR*INTR_DIM
#define SMROW    1288   // padded
#define XDIM     22     // OWN_DIM + N_HEADS*HEAD_DIM
#define H1DIM    256
#define H2DIM    256

__device__ __forceinline__ float fast_tanhf(float x) {
    // tanh(x) = 1 - 2/(exp(2x)+1); exact at +-inf saturation, ~1e-7 abs error
    float e = __expf(2.0f * x);
    return 1.0f - 2.0f / (e + 1.0f);
}

__device__ __forceinline__ float leaky02(float x) {
    return fmaxf(x, 0.2f * x);
}

// ---------------- Kernel A: attention + layernorm -> x (B x 22) ----------------
// one wave per sample, 4 samples per 256-thread block.
// All hot-loop weights register-resident (Wk 75 + va 15 + qb 15); V-projection
// deferred to after softmax via alpha-weighted xi sum.
__global__ __launch_bounds__(256, 2) void attn_ln_kernel(
    const float* __restrict__ obs,
    const float* __restrict__ Wq, const float* __restrict__ bq,
    const float* __restrict__ Wk, const float* __restrict__ bk,
    const float* __restrict__ Wv, const float* __restrict__ bv,
    const float* __restrict__ v_att, const float* __restrict__ temp,
    const float* __restrict__ ln_g, const float* __restrict__ ln_b,
    float* __restrict__ xout)
{
    __shared__ float sm[4][SMROW];
    const int wid  = threadIdx.x >> 6;
    const int lane = threadIdx.x & 63;
    const int s    = blockIdx.x * 4 + wid;

    const float* row = obs + (size_t)s * ROWLEN;
    float* smr = sm[wid];
    for (int i = lane; i < ROWLEN; i += 64) smr[i] = row[i];

    // ---- register-resident weights (wave-uniform values) ----
    const float fac = fabsf(temp[0]) * 0.4472135954999579f;  // |T| / sqrt(5)
    float wk[N_HEADS][INTR_DIM][HEAD_DIM];
    #pragma unroll
    for (int h = 0; h < N_HEADS; ++h)
        #pragma unroll
        for (int i = 0; i < INTR_DIM; ++i)
            #pragma unroll
            for (int d = 0; d < HEAD_DIM; ++d)
                wk[h][i][d] = Wk[h*INTR_DIM*HEAD_DIM + i*HEAD_DIM + d];
    float va[N_HEADS][HEAD_DIM];   // v_att pre-scaled by fac
    #pragma unroll
    for (int h = 0; h < N_HEADS; ++h)
        #pragma unroll
        for (int d = 0; d < HEAD_DIM; ++d)
            va[h][d] = v_att[h*HEAD_DIM + d] * fac;

    __syncthreads();

    // qb[h][d] = q + bk (q from own, redundant per lane; own broadcast from LDS)
    float qb[N_HEADS][HEAD_DIM];
    #pragma unroll
    for (int h = 0; h < N_HEADS; ++h) {
        #pragma unroll
        for (int d = 0; d < HEAD_DIM; ++d) {
            float a = bq[h*HEAD_DIM + d] + bk[h*HEAD_DIM + d];
            #pragma unroll
            for (int o = 0; o < OWN_DIM; ++o)
                a += smr[o] * Wq[h*OWN_DIM*HEAD_DIM + o*HEAD_DIM + d];
            qb[h][d] = a;
        }
    }

    // each lane owns items n = lane + 64*r (stride-5 LDS reads, 2-way = free)
    float xi[4][INTR_DIM];
    float ex[N_HEADS][4];           // exp(score) (0 for padded)
    #pragma unroll
    for (int r = 0; r < 4; ++r) {
        const int n = lane + 64*r;
        const float* it = smr + OWN_DIM + n*INTR_DIM;
        #pragma unroll
        for (int i = 0; i < INTR_DIM; ++i) xi[r][i] = it[i];
        float asum = fabsf(xi[r][0]) + fabsf(xi[r][1]) + fabsf(xi[r][2])
                   + fabsf(xi[r][3]) + fabsf(xi[r][4]);
        const bool pad = asum < 1e-6f;
        #pragma unroll
        for (int h = 0; h < N_HEADS; ++h) {
            float dot = 0.0f;
            #pragma unroll
            for (int d = 0; d < HEAD_DIM; ++d) {
                float t = qb[h][d];
                #pragma unroll
                for (int i = 0; i < INTR_DIM; ++i)
                    t = fmaf(xi[r][i], wk[h][i][d], t);
                dot = fmaf(fast_tanhf(t), va[h][d], dot);
            }
            // no max-subtraction: |score| <= sum|va| (small), exp safe in fp32
            ex[h][r] = pad ? 0.0f : __expf(dot);
        }
    }

    // per-head softmax denominator (4 local + 64-lane butterfly)
    float al[N_HEADS][4];
    float live[N_HEADS];
    #pragma unroll
    for (int h = 0; h < N_HEADS; ++h) {
        float ssum = (ex[h][0] + ex[h][1]) + (ex[h][2] + ex[h][3]);
        #pragma unroll
        for (int o = 1; o < 64; o <<= 1) ssum += __shfl_xor(ssum, o, 64);
        const float rinv = ssum > 0.0f ? 1.0f / ssum : 0.0f;
        live[h] = ssum > 0.0f ? 1.0f : 0.0f;
        #pragma unroll
        for (int r = 0; r < 4; ++r) al[h][r] = ex[h][r] * rinv;
    }

    // alpha-weighted xi sums: sv[h][i] = sum_n alpha_hn * xi_n[i]
    float sv[N_HEADS][INTR_DIM] = {};
    #pragma unroll
    for (int r = 0; r < 4; ++r)
        #pragma unroll
        for (int h = 0; h < N_HEADS; ++h) {
            const float a = al[h][r];
            #pragma unroll
            for (int i = 0; i < INTR_DIM; ++i)
                sv[h][i] = fmaf(a, xi[r][i], sv[h][i]);
        }
    // butterfly-reduce the 15 sums; all lanes end with totals
    #pragma unroll
    for (int h = 0; h < N_HEADS; ++h)
        #pragma unroll
        for (int i = 0; i < INTR_DIM; ++i) {
            float v = sv[h][i];
            #pragma unroll
            for (int o = 1; o < 64; o <<= 1) v += __shfl_xor(v, o, 64);
            sv[h][i] = v;
        }

    // deferred V projection: ctx = sv @ Wv + bv * live  (once per lane, cheap)
    float ctx[N_HEADS][HEAD_DIM];
    #pragma unroll
    for (int h = 0; h < N_HEADS; ++h)
        #pragma unroll
        for (int d = 0; d < HEAD_DIM; ++d) {
            float c = bv[h*HEAD_DIM + d] * live[h];
            #pragma unroll
            for (int i = 0; i < INTR_DIM; ++i)
                c = fmaf(sv[h][i], Wv[h*INTR_DIM*HEAD_DIM + i*HEAD_DIM + d], c);
            ctx[h][d] = c;
        }

    // layernorm over x = [own(7), ctx(15)] computed redundantly per lane
    float xv7[OWN_DIM];
    #pragma unroll
    for (int o = 0; o < OWN_DIM; ++o) xv7[o] = smr[o];
    float sum = 0.0f;
    #pragma unroll
    for (int o = 0; o < OWN_DIM; ++o) sum += xv7[o];
    #pragma unroll
    for (int h = 0; h < N_HEADS; ++h)
        #pragma unroll
        for (int d = 0; d < HEAD_DIM; ++d) sum += ctx[h][d];
    const float mu = sum * (1.0f / 22.0f);
    float var = 0.0f;
    #pragma unroll
    for (int o = 0; o < OWN_DIM; ++o) { float dd = xv7[o] - mu; var += dd*dd; }
    #pragma unroll
    for (int h = 0; h < N_HEADS; ++h)
        #pragma unroll
        for (int d = 0; d < HEAD_DIM; ++d) { float dd = ctx[h][d] - mu; var += dd*dd; }
    var *= (1.0f / 22.0f);
    const float rs = rsqrtf(var + 1e-5f);

    // lane j < 22 writes element j (static cndmask select chain, coalesced store)
    float xv = xv7[0];
    #pragma unroll
    for (int o = 1; o < OWN_DIM; ++o) xv = (lane == o) ? xv7[o] : xv;
    #pragma unroll
    for (int j = 0; j < 15; ++j) xv = (lane == OWN_DIM + j) ? ctx[j/5][j%5] : xv;
    if (lane < XDIM) {
        xout[(size_t)s * XDIM + lane] = (xv - mu) * rs * ln_g[lane] + ln_b[lane];
    }
}

// ---------------- Kernel B: MLP 22->256->256->2 (+log_std) ----------------
// 32 samples per 256-thread block; thread owns 8 samples x 4 contiguous cols
__global__ __launch_bounds__(256) void mlp_kernel(
    const float* __restrict__ x,
    const float* __restrict__ W1, const float* __restrict__ b1,
    const float* __restrict__ W2, const float* __restrict__ b2,
    const float* __restrict__ Wf, const float* __restrict__ bf,
    const float* __restrict__ lstd, float* __restrict__ out)
{
    __shared__ __align__(16) float xs[32 * XDIM];       //  2.8 KB
    __shared__ __align__(16) float h1s[32 * H1DIM];     // 32 KB
    __shared__ __align__(16) float w2s[16 * H2DIM];     // 16 KB (K-chunk of W2)
    __shared__ __align__(16) float wfs[H2DIM * 2];      //  2 KB

    const int t   = threadIdx.x;
    const int blk = blockIdx.x;

    for (int i = t; i < 32 * XDIM; i += 256) xs[i] = x[(size_t)blk * 32 * XDIM + i];
    for (int i = t; i < H2DIM * 2; i += 256) wfs[i] = Wf[i];

    // layer 1: thread t computes h1[:, t]; W1 column preloaded in regs
    float w1r[XDIM];
    #pragma unroll
    for (int i = 0; i < XDIM; ++i) w1r[i] = W1[i * H1DIM + t];
    const float b1t = b1[t];
    __syncthreads();
    for (int e = 0; e < 32; ++e) {
        float a = b1t;
        #pragma unroll
        for (int i = 0; i < XDIM; ++i) a += xs[e * XDIM + i] * w1r[i];
        h1s[e * H1DIM + t] = leaky02(a);
    }

    // layer 2: K-chunked; conflict-free (W2 reads lane-contiguous, h1 reads uniform)
    const int wid  = t >> 6;
    const int lane = t & 63;
    const int s0 = wid * 8;       // 8 samples per thread
    const int j0 = lane * 4;      // 4 contiguous cols per thread

    float4 b2v = *(const float4*)&b2[j0];
    float acc[8][4];
    #pragma unroll
    for (int si = 0; si < 8; ++si) {
        acc[si][0] = b2v.x; acc[si][1] = b2v.y; acc[si][2] = b2v.z; acc[si][3] = b2v.w;
    }

    for (int kc = 0; kc < 16; ++kc) {
        __syncthreads();
        #pragma unroll
        for (int i = 0; i < 16; ++i)
            w2s[i * H2DIM + t] = W2[(size_t)(kc * 16 + i) * H2DIM + t];
        __syncthreads();
        #pragma unroll
        for (int k = 0; k < 16; k += 4) {
            float4 h4[8];
            #pragma unroll
            for (int si = 0; si < 8; ++si)
                h4[si] = *(const float4*)&h1s[(s0 + si) * H1DIM + kc * 16 + k];
            #pragma unroll
            for (int dk = 0; dk < 4; ++dk) {
                float4 w = *(const float4*)&w2s[(k + dk) * H2DIM + j0];
                #pragma unroll
                for (int si = 0; si < 8; ++si) {
                    float hv = (dk == 0) ? h4[si].x : (dk == 1) ? h4[si].y
                             : (dk == 2) ? h4[si].z : h4[si].w;
                    acc[si][0] = fmaf(hv, w.x, acc[si][0]);
                    acc[si][1] = fmaf(hv, w.y, acc[si][1]);
                    acc[si][2] = fmaf(hv, w.z, acc[si][2]);
                    acc[si][3] = fmaf(hv, w.w, acc[si][3]);
                }
            }
        }
    }

    // layer 3: partial out per thread, wave-reduce over the 64 col-group lanes
    float p[8][2] = {};
    #pragma unroll
    for (int si = 0; si < 8; ++si) {
        #pragma unroll
        for (int jj = 0; jj < 4; ++jj) {
            float h2v = leaky02(acc[si][jj]);
            p[si][0] += h2v * wfs[(j0 + jj) * 2 + 0];
            p[si][1] += h2v * wfs[(j0 + jj) * 2 + 1];
        }
    }
    #pragma unroll
    for (int o = 1; o < 64; o <<= 1) {
        #pragma unroll
        for (int si = 0; si < 8; ++si) {
            p[si][0] += __shfl_xor(p[si][0], o, 64);
            p[si][1] += __shfl_xor(p[si][1], o, 64);
        }
    }
    if (lane == 0) {
        const float bf0 = bf[0], bf1 = bf[1];
        const float ls0 = lstd[0], ls1 = lstd[1];
        #pragma unroll
        for (int si = 0; si < 8; ++si) {
            const int srow = blk * 32 + s0 + si;
            float4 o4;
            o4.x = p[si][0] + bf0;
            o4.y = p[si][1] + bf1;
            o4.z = ls0;
            o4.w = ls1;
            *(float4*)&out[(size_t)srow * 4] = o4;
        }
    }
}

extern "C" void kernel_launch(void* const* d_in, const int* in_sizes, int n_in,
                              void* d_out, int out_size, void* d_ws, size_t ws_size,
                              hipStream_t stream) {
    const float* obs   = (const float*)d_in[0];
    const float* Wq    = (const float*)d_in[1];
    const float* bq    = (const float*)d_in[2];
    const float* Wk    = (const float*)d_in[3];
    const float* bk    = (const float*)d_in[4];
    const float* Wv    = (const float*)d_in[5];
    const float* bv    = (const float*)d_in[6];
    const float* v_att = (const float*)d_in[7];
    const float* temp  = (const float*)d_in[8];
    const float* ln_g  = (const float*)d_in[9];
    const float* ln_b  = (const float*)d_in[10];
    const float* W1    = (const float*)d_in[11];
    const float* b1    = (const float*)d_in[12];
    const float* W2    = (const float*)d_in[13];
    const float* b2    = (const float*)d_in[14];
    const float* Wf    = (const float*)d_in[15];
    const float* bf    = (const float*)d_in[16];
    const float* lstd  = (const float*)d_in[17];

    float* xbuf = (float*)d_ws;   // B x 22 normalized features (2.88 MB)
    float* outf = (float*)d_out;

    attn_ln_kernel<<<NBATCH / 4, 256, 0, stream>>>(
        obs, Wq, bq, Wk, bk, Wv, bv, v_att, temp, ln_g, ln_b, xbuf);
    mlp_kernel<<<NBATCH / 32, 256, 0, stream>>>(
        xbuf, W1, b1, W2, b2, Wf, bf, lstd, outf);
}

// Round 4
// 153.893 us; speedup vs baseline: 1.6465x; 1.2907x over previous
//
#include <hip/hip_runtime.h>
#include <math.h>

// Problem constants
#define NBATCH   32768
#define OWN_DIM  7
#define INTR_DIM 5
#define N_HEADS  3
#define HEAD_DIM 5
#define N_INTR   256
#define ROWLEN   1287   // OWN_DIM + N_INTR*INTR_DIM
#define XDIM     22     // OWN_DIM + N_HEADS*HEAD_DIM
#define H1DIM    256
#define H2DIM    256

__device__ __forceinline__ float fast_tanh(float x) {
    // tanh(x) = 1 - 2/(exp2(2*log2e*x)+1); v_exp + v_rcp only (no full-prec div)
    float e = __builtin_amdgcn_exp2f(x * 2.885390081777927f);
    return 1.0f - 2.0f * __builtin_amdgcn_rcpf(e + 1.0f);
}

__device__ __forceinline__ float leaky02(float x) {
    return fmaxf(x, 0.2f * x);
}

// ---------------- Kernel A: attention + layernorm -> x (B x 22) ----------------
// one wave per sample, 4 samples per 256-thread block.
// Head-outer loop with compile-time head index: per-head weights (25) have
// uniform constant addresses -> scalar regs; softmax normalization deferred
// past a single combined 18-value butterfly reduction.
__global__ __launch_bounds__(256, 4) void attn_ln_kernel(
    const float* __restrict__ obs,
    const float* __restrict__ Wq, const float* __restrict__ bq,
    const float* __restrict__ Wk, const float* __restrict__ bk,
    const float* __restrict__ Wv, const float* __restrict__ bv,
    const float* __restrict__ v_att, const float* __restrict__ temp,
    const float* __restrict__ ln_g, const float* __restrict__ ln_b,
    float* __restrict__ xout)
{
    __shared__ float smblk[4 * ROWLEN];   // 4 rows contiguous, float4-stageable
    const int wid  = threadIdx.x >> 6;
    const int lane = threadIdx.x & 63;
    const int s    = blockIdx.x * 4 + wid;

    // cooperative float4 staging of the block's 4 rows (5148 floats, 16B-aligned)
    {
        const float4* src = (const float4*)(obs + (size_t)blockIdx.x * 4 * ROWLEN);
        float4* dst = (float4*)smblk;
        for (int i = threadIdx.x; i < ROWLEN; i += 256) dst[i] = src[i];
    }
    __syncthreads();

    const float* smr = smblk + wid * ROWLEN;
    const float fac = fabsf(temp[0]) * 0.4472135954999579f;      // |T|/sqrt(5)
    const float facl2e = fac * 1.4426950408889634f;              // folded log2e

    // per-lane items n = lane + 64*r (stride-5 LDS reads, 2 lanes/bank = free)
    float xi[4][INTR_DIM];
    float npf[4];                   // 0 if padded else 1
    #pragma unroll
    for (int r = 0; r < 4; ++r) {
        const float* it = smr + OWN_DIM + (lane + 64*r) * INTR_DIM;
        #pragma unroll
        for (int i = 0; i < INTR_DIM; ++i) xi[r][i] = it[i];
        float asum = fabsf(xi[r][0]) + fabsf(xi[r][1]) + fabsf(xi[r][2])
                   + fabsf(xi[r][3]) + fabsf(xi[r][4]);
        npf[r] = (asum < 1e-6f) ? 0.0f : 1.0f;
    }

    float svp[N_HEADS][INTR_DIM];   // sum_n ex_n * xi_n[i]  (pre-normalized)
    float es[N_HEADS];              // sum_n ex_n

    #pragma unroll
    for (int h = 0; h < N_HEADS; ++h) {     // h compile-time constant
        // per-head weights: constant uniform addresses
        float wk[INTR_DIM][HEAD_DIM];
        #pragma unroll
        for (int i = 0; i < INTR_DIM; ++i)
            #pragma unroll
            for (int d = 0; d < HEAD_DIM; ++d)
                wk[i][d] = Wk[h*INTR_DIM*HEAD_DIM + i*HEAD_DIM + d];
        float va[HEAD_DIM];
        #pragma unroll
        for (int d = 0; d < HEAD_DIM; ++d)
            va[d] = v_att[h*HEAD_DIM + d] * facl2e;
        // qb = q + bk (own broadcast from LDS; Wq uniform)
        float qb[HEAD_DIM];
        #pragma unroll
        for (int d = 0; d < HEAD_DIM; ++d) {
            float a = bq[h*HEAD_DIM + d] + bk[h*HEAD_DIM + d];
            #pragma unroll
            for (int o = 0; o < OWN_DIM; ++o)
                a = fmaf(smr[o], Wq[h*OWN_DIM*HEAD_DIM + o*HEAD_DIM + d], a);
            qb[d] = a;
        }

        float sv0 = 0.f, sv1 = 0.f, sv2 = 0.f, sv3 = 0.f, sv4 = 0.f, esum = 0.f;
        #pragma unroll
        for (int r = 0; r < 4; ++r) {
            float dot = 0.0f;
            #pragma unroll
            for (int d = 0; d < HEAD_DIM; ++d) {
                float t = qb[d];
                #pragma unroll
                for (int i = 0; i < INTR_DIM; ++i)
                    t = fmaf(xi[r][i], wk[i][d], t);
                dot = fmaf(fast_tanh(t), va[d], dot);
            }
            // no max-subtraction (|score*log2e| small); padded -> 0
            float e = npf[r] * __builtin_amdgcn_exp2f(dot);
            esum += e;
            sv0 = fmaf(e, xi[r][0], sv0);
            sv1 = fmaf(e, xi[r][1], sv1);
            sv2 = fmaf(e, xi[r][2], sv2);
            sv3 = fmaf(e, xi[r][3], sv3);
            sv4 = fmaf(e, xi[r][4], sv4);
        }
        svp[h][0] = sv0; svp[h][1] = sv1; svp[h][2] = sv2;
        svp[h][3] = sv3; svp[h][4] = sv4; es[h] = esum;
    }

    // combined butterfly over 18 values; all lanes end with totals
    #pragma unroll
    for (int o = 1; o < 64; o <<= 1) {
        #pragma unroll
        for (int h = 0; h < N_HEADS; ++h) {
            es[h] += __shfl_xor(es[h], o, 64);
            #pragma unroll
            for (int i = 0; i < INTR_DIM; ++i)
                svp[h][i] += __shfl_xor(svp[h][i], o, 64);
        }
    }

    // normalize + deferred V projection: ctx = (svp/es) @ Wv + bv*live
    float ctx[N_HEADS][HEAD_DIM];
    #pragma unroll
    for (int h = 0; h < N_HEADS; ++h) {
        const float live = (es[h] > 0.0f) ? 1.0f : 0.0f;
        const float rinv = live * __builtin_amdgcn_rcpf(es[h]);
        float svn[INTR_DIM];
        #pragma unroll
        for (int i = 0; i < INTR_DIM; ++i) svn[i] = svp[h][i] * rinv;
        #pragma unroll
        for (int d = 0; d < HEAD_DIM; ++d) {
            float c = bv[h*HEAD_DIM + d] * live;
            #pragma unroll
            for (int i = 0; i < INTR_DIM; ++i)
                c = fmaf(svn[i], Wv[h*INTR_DIM*HEAD_DIM + i*HEAD_DIM + d], c);
            ctx[h][d] = c;
        }
    }

    // layernorm over x = [own(7), ctx(15)] computed redundantly per lane
    float xv7[OWN_DIM];
    #pragma unroll
    for (int o = 0; o < OWN_DIM; ++o) xv7[o] = smr[o];
    float sum = 0.0f;
    #pragma unroll
    for (int o = 0; o < OWN_DIM; ++o) sum += xv7[o];
    #pragma unroll
    for (int h = 0; h < N_HEADS; ++h)
        #pragma unroll
        for (int d = 0; d < HEAD_DIM; ++d) sum += ctx[h][d];
    const float mu = sum * (1.0f / 22.0f);
    float var = 0.0f;
    #pragma unroll
    for (int o = 0; o < OWN_DIM; ++o) { float dd = xv7[o] - mu; var += dd*dd; }
    #pragma unroll
    for (int h = 0; h < N_HEADS; ++h)
        #pragma unroll
        for (int d = 0; d < HEAD_DIM; ++d) { float dd = ctx[h][d] - mu; var += dd*dd; }
    var *= (1.0f / 22.0f);
    const float rs = rsqrtf(var + 1e-5f);

    // lane j < 22 writes element j (static cndmask select chain, coalesced store)
    float xv = xv7[0];
    #pragma unroll
    for (int o = 1; o < OWN_DIM; ++o) xv = (lane == o) ? xv7[o] : xv;
    #pragma unroll
    for (int j = 0; j < 15; ++j) xv = (lane == OWN_DIM + j) ? ctx[j/5][j%5] : xv;
    if (lane < XDIM) {
        xout[(size_t)s * XDIM + lane] = (xv - mu) * rs * ln_g[lane] + ln_b[lane];
    }
}

// ---------------- Kernel B: MLP 22->256->256->2 (+log_std) ----------------
// (unchanged this round — isolating the attn rewrite)
__global__ __launch_bounds__(256) void mlp_kernel(
    const float* __restrict__ x,
    const float* __restrict__ W1, const float* __restrict__ b1,
    const float* __restrict__ W2, const float* __restrict__ b2,
    const float* __restrict__ Wf, const float* __restrict__ bf,
    const float* __restrict__ lstd, float* __restrict__ out)
{
    __shared__ __align__(16) float xs[32 * XDIM];
    __shared__ __align__(16) float h1s[32 * H1DIM];
    __shared__ __align__(16) float w2s[16 * H2DIM];
    __shared__ __align__(16) float wfs[H2DIM * 2];

    const int t   = threadIdx.x;
    const int blk = blockIdx.x;

    for (int i = t; i < 32 * XDIM; i += 256) xs[i] = x[(size_t)blk * 32 * XDIM + i];
    for (int i = t; i < H2DIM * 2; i += 256) wfs[i] = Wf[i];

    float w1r[XDIM];
    #pragma unroll
    for (int i = 0; i < XDIM; ++i) w1r[i] = W1[i * H1DIM + t];
    const float b1t = b1[t];
    __syncthreads();
    for (int e = 0; e < 32; ++e) {
        float a = b1t;
        #pragma unroll
        for (int i = 0; i < XDIM; ++i) a += xs[e * XDIM + i] * w1r[i];
        h1s[e * H1DIM + t] = leaky02(a);
    }

    const int wid  = t >> 6;
    const int lane = t & 63;
    const int s0 = wid * 8;
    const int j0 = lane * 4;

    float4 b2v = *(const float4*)&b2[j0];
    float acc[8][4];
    #pragma unroll
    for (int si = 0; si < 8; ++si) {
        acc[si][0] = b2v.x; acc[si][1] = b2v.y; acc[si][2] = b2v.z; acc[si][3] = b2v.w;
    }

    for (int kc = 0; kc < 16; ++kc) {
        __syncthreads();
        #pragma unroll
        for (int i = 0; i < 16; ++i)
            w2s[i * H2DIM + t] = W2[(size_t)(kc * 16 + i) * H2DIM + t];
        __syncthreads();
        #pragma unroll
        for (int k = 0; k < 16; k += 4) {
            float4 h4[8];
            #pragma unroll
            for (int si = 0; si < 8; ++si)
                h4[si] = *(const float4*)&h1s[(s0 + si) * H1DIM + kc * 16 + k];
            #pragma unroll
            for (int dk = 0; dk < 4; ++dk) {
                float4 w = *(const float4*)&w2s[(k + dk) * H2DIM + j0];
                #pragma unroll
                for (int si = 0; si < 8; ++si) {
                    float hv = (dk == 0) ? h4[si].x : (dk == 1) ? h4[si].y
                             : (dk == 2) ? h4[si].z : h4[si].w;
                    acc[si][0] = fmaf(hv, w.x, acc[si][0]);
                    acc[si][1] = fmaf(hv, w.y, acc[si][1]);
                    acc[si][2] = fmaf(hv, w.z, acc[si][2]);
                    acc[si][3] = fmaf(hv, w.w, acc[si][3]);
                }
            }
        }
    }

    float p[8][2] = {};
    #pragma unroll
    for (int si = 0; si < 8; ++si) {
        #pragma unroll
        for (int jj = 0; jj < 4; ++jj) {
            float h2v = leaky02(acc[si][jj]);
            p[si][0] += h2v * wfs[(j0 + jj) * 2 + 0];
            p[si][1] += h2v * wfs[(j0 + jj) * 2 + 1];
        }
    }
    #pragma unroll
    for (int o = 1; o < 64; o <<= 1) {
        #pragma unroll
        for (int si = 0; si < 8; ++si) {
            p[si][0] += __shfl_xor(p[si][0], o, 64);
            p[si][1] += __shfl_xor(p[si][1], o, 64);
        }
    }
    if (lane == 0) {
        const float bf0 = bf[0], bf1 = bf[1];
        const float ls0 = lstd[0], ls1 = lstd[1];
        #pragma unroll
        for (int si = 0; si < 8; ++si) {
            const int srow = blk * 32 + s0 + si;
            float4 o4;
            o4.x = p[si][0] + bf0;
            o4.y = p[si][1] + bf1;
            o4.z = ls0;
            o4.w = ls1;
            *(float4*)&out[(size_t)srow * 4] = o4;
        }
    }
}

extern "C" void kernel_launch(void* const* d_in, const int* in_sizes, int n_in,
                              void* d_out, int out_size, void* d_ws, size_t ws_size,
                              hipStream_t stream) {
    const float* obs   = (const float*)d_in[0];
    const float* Wq    = (const float*)d_in[1];
    const float* bq    = (const float*)d_in[2];
    const float* Wk    = (const float*)d_in[3];
    const float* bk    = (const float*)d_in[4];
    const float* Wv    = (const float*)d_in[5];
    const float* bv    = (const float*)d_in[6];
    const float* v_att = (const float*)d_in[7];
    const float* temp  = (const float*)d_in[8];
    const float* ln_g  = (const float*)d_in[9];
    const float* ln_b  = (const float*)d_in[10];
    const float* W1    = (const float*)d_in[11];
    const float* b1    = (const float*)d_in[12];
    const float* W2    = (const float*)d_in[13];
    const float* b2    = (const float*)d_in[14];
    const float* Wf    = (const float*)d_in[15];
    const float* bf    = (const float*)d_in[16];
    const float* lstd  = (const float*)d_in[17];

    float* xbuf = (float*)d_ws;   // B x 22 normalized features (2.88 MB)
    float* outf = (float*)d_out;

    attn_ln_kernel<<<NBATCH / 4, 256, 0, stream>>>(
        obs, Wq, bq, Wk, bk, Wv, bv, v_att, temp, ln_g, ln_b, xbuf);
    mlp_kernel<<<NBATCH / 32, 256, 0, stream>>>(
        xbuf, W1, b1, W2, b2, Wf, bf, lstd, outf);
}

// Round 5
// 122.860 us; speedup vs baseline: 2.0623x; 1.2526x over previous
//
#include <hip/hip_runtime.h>
#include <math.h>

// Problem constants
#define NBATCH   32768
#define OWN_DIM  7
#define INTR_DIM 5
#define N_HEADS  3
#define HEAD_DIM 5
#define N_INTR   256
#define ROWLEN   1287   // OWN_DIM + N_INTR*INTR_DIM
#define XDIM     22     // OWN_DIM + N_HEADS*HEAD_DIM
#define H1DIM    256
#define H2DIM    256

// LDS weight-pack offsets (attn kernel)
#define WQ_OFF   0     // 105 = 3*7*5
#define BQ_OFF   105   // 15
#define BK_OFF   120   // 15
#define WK_OFF   135   // 75
#define WV_OFF   210   // 75
#define BV_OFF   285   // 15
#define VA_OFF   300   // 15
#define WL_SIZE  315

typedef __attribute__((ext_vector_type(8))) short bf16x8;
typedef __attribute__((ext_vector_type(4))) float f32x4;

__device__ __forceinline__ float fast_tanh(float x) {
    // tanh(x) = 1 - 2/(exp2(2*log2e*x)+1); v_exp + v_rcp only
    float e = __builtin_amdgcn_exp2f(x * 2.885390081777927f);
    return 1.0f - 2.0f * __builtin_amdgcn_rcpf(e + 1.0f);
}

__device__ __forceinline__ float leaky02(float x) {
    return fmaxf(x, 0.2f * x);
}

__device__ __forceinline__ unsigned short f2bf_rne(float f) {
    unsigned u = __float_as_uint(f);
    return (unsigned short)((u + 0x7FFFu + ((u >> 16) & 1u)) >> 16);
}

// ---------------- Kernel A: attention + layernorm -> x (B x 22) ----------------
// one wave per sample, 4 samples per 256-thread block.
// All weights staged once into LDS (value-identical; kills per-head
// scalar/global-load latency chains in the unrolled loops).
__global__ __launch_bounds__(256, 4) void attn_ln_kernel(
    const float* __restrict__ obs,
    const float* __restrict__ Wq, const float* __restrict__ bq,
    const float* __restrict__ Wk, const float* __restrict__ bk,
    const float* __restrict__ Wv, const float* __restrict__ bv,
    const float* __restrict__ v_att, const float* __restrict__ temp,
    const float* __restrict__ ln_g, const float* __restrict__ ln_b,
    float* __restrict__ xout)
{
    __shared__ float smblk[4 * ROWLEN];   // 4 rows contiguous
    __shared__ float wl[WL_SIZE];
    const int wid  = threadIdx.x >> 6;
    const int lane = threadIdx.x & 63;
    const int s    = blockIdx.x * 4 + wid;

    // cooperative float4 staging of the block's 4 rows (5148 floats)
    {
        const float4* src = (const float4*)(obs + (size_t)blockIdx.x * 4 * ROWLEN);
        float4* dst = (float4*)smblk;
        for (int i = threadIdx.x; i < ROWLEN; i += 256) dst[i] = src[i];
    }
    // weight pack -> LDS (one time per block)
    {
        const int t = threadIdx.x;
        if (t < 105) wl[WQ_OFF + t] = Wq[t];
        if (t < 15)  wl[BQ_OFF + t] = bq[t];
        if (t < 15)  wl[BK_OFF + t] = bk[t];
        if (t < 75)  wl[WK_OFF + t] = Wk[t];
        if (t < 75)  wl[WV_OFF + t] = Wv[t];
        if (t < 15)  wl[BV_OFF + t] = bv[t];
        if (t < 15)  wl[VA_OFF + t] = v_att[t];
    }
    __syncthreads();

    const float* smr = smblk + wid * ROWLEN;
    const float fac = fabsf(temp[0]) * 0.4472135954999579f;      // |T|/sqrt(5)
    const float facl2e = fac * 1.4426950408889634f;              // folded log2e

    // per-lane items n = lane + 64*r (stride-5 LDS reads, 2 lanes/bank = free)
    float xi[4][INTR_DIM];
    float npf[4];                   // 0 if padded else 1
    #pragma unroll
    for (int r = 0; r < 4; ++r) {
        const float* it = smr + OWN_DIM + (lane + 64*r) * INTR_DIM;
        #pragma unroll
        for (int i = 0; i < INTR_DIM; ++i) xi[r][i] = it[i];
        float asum = fabsf(xi[r][0]) + fabsf(xi[r][1]) + fabsf(xi[r][2])
                   + fabsf(xi[r][3]) + fabsf(xi[r][4]);
        npf[r] = (asum < 1e-6f) ? 0.0f : 1.0f;
    }

    float svp[N_HEADS][INTR_DIM];   // sum_n ex_n * xi_n[i]  (pre-normalized)
    float es[N_HEADS];              // sum_n ex_n

    #pragma unroll
    for (int h = 0; h < N_HEADS; ++h) {     // h compile-time constant
        // per-head weights from LDS (wave-uniform broadcast reads)
        float wk[INTR_DIM][HEAD_DIM];
        #pragma unroll
        for (int i = 0; i < INTR_DIM; ++i)
            #pragma unroll
            for (int d = 0; d < HEAD_DIM; ++d)
                wk[i][d] = wl[WK_OFF + h*25 + i*5 + d];
        float va[HEAD_DIM];
        #pragma unroll
        for (int d = 0; d < HEAD_DIM; ++d)
            va[d] = wl[VA_OFF + h*5 + d] * facl2e;
        // qb = q + bk (own broadcast from LDS)
        float qb[HEAD_DIM];
        #pragma unroll
        for (int d = 0; d < HEAD_DIM; ++d) {
            float a = wl[BQ_OFF + h*5 + d] + wl[BK_OFF + h*5 + d];
            #pragma unroll
            for (int o = 0; o < OWN_DIM; ++o)
                a = fmaf(smr[o], wl[WQ_OFF + h*35 + o*5 + d], a);
            qb[d] = a;
        }

        float sv0 = 0.f, sv1 = 0.f, sv2 = 0.f, sv3 = 0.f, sv4 = 0.f, esum = 0.f;
        #pragma unroll
        for (int r = 0; r < 4; ++r) {
            float dot = 0.0f;
            #pragma unroll
            for (int d = 0; d < HEAD_DIM; ++d) {
                float t = qb[d];
                #pragma unroll
                for (int i = 0; i < INTR_DIM; ++i)
                    t = fmaf(xi[r][i], wk[i][d], t);
                dot = fmaf(fast_tanh(t), va[d], dot);
            }
            float e = npf[r] * __builtin_amdgcn_exp2f(dot);
            esum += e;
            sv0 = fmaf(e, xi[r][0], sv0);
            sv1 = fmaf(e, xi[r][1], sv1);
            sv2 = fmaf(e, xi[r][2], sv2);
            sv3 = fmaf(e, xi[r][3], sv3);
            sv4 = fmaf(e, xi[r][4], sv4);
        }
        svp[h][0] = sv0; svp[h][1] = sv1; svp[h][2] = sv2;
        svp[h][3] = sv3; svp[h][4] = sv4; es[h] = esum;
    }

    // combined butterfly over 18 values; all lanes end with totals
    #pragma unroll
    for (int o = 1; o < 64; o <<= 1) {
        #pragma unroll
        for (int h = 0; h < N_HEADS; ++h) {
            es[h] += __shfl_xor(es[h], o, 64);
            #pragma unroll
            for (int i = 0; i < INTR_DIM; ++i)
                svp[h][i] += __shfl_xor(svp[h][i], o, 64);
        }
    }

    // normalize + deferred V projection: ctx = (svp/es) @ Wv + bv*live
    float ctx[N_HEADS][HEAD_DIM];
    #pragma unroll
    for (int h = 0; h < N_HEADS; ++h) {
        const float live = (es[h] > 0.0f) ? 1.0f : 0.0f;
        const float rinv = live * __builtin_amdgcn_rcpf(es[h]);
        float svn[INTR_DIM];
        #pragma unroll
        for (int i = 0; i < INTR_DIM; ++i) svn[i] = svp[h][i] * rinv;
        #pragma unroll
        for (int d = 0; d < HEAD_DIM; ++d) {
            float c = wl[BV_OFF + h*5 + d] * live;
            #pragma unroll
            for (int i = 0; i < INTR_DIM; ++i)
                c = fmaf(svn[i], wl[WV_OFF + h*25 + i*5 + d], c);
            ctx[h][d] = c;
        }
    }

    // layernorm over x = [own(7), ctx(15)] computed redundantly per lane
    float xv7[OWN_DIM];
    #pragma unroll
    for (int o = 0; o < OWN_DIM; ++o) xv7[o] = smr[o];
    float sum = 0.0f;
    #pragma unroll
    for (int o = 0; o < OWN_DIM; ++o) sum += xv7[o];
    #pragma unroll
    for (int h = 0; h < N_HEADS; ++h)
        #pragma unroll
        for (int d = 0; d < HEAD_DIM; ++d) sum += ctx[h][d];
    const float mu = sum * (1.0f / 22.0f);
    float var = 0.0f;
    #pragma unroll
    for (int o = 0; o < OWN_DIM; ++o) { float dd = xv7[o] - mu; var += dd*dd; }
    #pragma unroll
    for (int h = 0; h < N_HEADS; ++h)
        #pragma unroll
        for (int d = 0; d < HEAD_DIM; ++d) { float dd = ctx[h][d] - mu; var += dd*dd; }
    var *= (1.0f / 22.0f);
    const float rs = rsqrtf(var + 1e-5f);

    // lane j < 22 writes element j (static cndmask select chain, coalesced store)
    float xv = xv7[0];
    #pragma unroll
    for (int o = 1; o < OWN_DIM; ++o) xv = (lane == o) ? xv7[o] : xv;
    #pragma unroll
    for (int j = 0; j < 15; ++j) xv = (lane == OWN_DIM + j) ? ctx[j/5][j%5] : xv;
    if (lane < XDIM) {
        xout[(size_t)s * XDIM + lane] = (xv - mu) * rs * ln_g[lane] + ln_b[lane];
    }
}

// ---------------- Kernel B: MLP 22->256->256->2 (+log_std) ----------------
// 32 samples per 256-thread block. Layer 2 via bf16 MFMA (fp32 accum):
// h1 bf16 in LDS [m][k] (swizzled), W2 bf16 transposed [n][k]-chunks (swizzled).
// A/B fragment k-ordering errors cancel (sum over k, symmetric layouts);
// only row/col = lane&15 must hold (consistent with verified C/D layout).
__global__ __launch_bounds__(256) void mlp_kernel(
    const float* __restrict__ x,
    const float* __restrict__ W1, const float* __restrict__ b1,
    const float* __restrict__ W2, const float* __restrict__ b2,
    const float* __restrict__ Wf, const float* __restrict__ bf,
    const float* __restrict__ lstd, float* __restrict__ out)
{
    __shared__ __align__(16) float xs[32 * XDIM];              //  2.8 KB
    __shared__ __align__(16) unsigned char h1b[32 * 256 * 2];  // 16 KB bf16 [m][k]
    __shared__ __align__(16) unsigned char w2b[256 * 64 * 2];  // 32 KB bf16 [n][kchunk]
    __shared__ __align__(16) float wfs[H2DIM * 2];             //  2 KB
    __shared__ float oacc[4][32][2];                           //  1 KB

    const int t   = threadIdx.x;
    const int blk = blockIdx.x;

    for (int i = t; i < 32 * XDIM; i += 256) xs[i] = x[(size_t)blk * 32 * XDIM + i];
    for (int i = t; i < H2DIM * 2; i += 256) wfs[i] = Wf[i];

    // ---- layer 1: thread t computes h1[:, t] -> bf16 LDS column ----
    float w1r[XDIM];
    #pragma unroll
    for (int i = 0; i < XDIM; ++i) w1r[i] = W1[i * H1DIM + t];
    const float b1t = b1[t];
    __syncthreads();
    for (int e = 0; e < 32; ++e) {
        float a = b1t;
        #pragma unroll
        for (int i = 0; i < XDIM; ++i) a += xs[e * XDIM + i] * w1r[i];
        a = leaky02(a);
        int byte = e * 512 + t * 2;
        byte ^= ((e & 7) << 4);
        *(unsigned short*)(h1b + byte) = f2bf_rne(a);
    }

    // ---- layer 2: C[32][256] = h1 @ W2 via MFMA; wave owns 64-col slab ----
    const int wv_  = t >> 6;          // wave id -> n-slab base wv_*64
    const int lane = t & 63;
    const int mrow = lane & 15;       // A-row / B-col within 16-tile
    const int qk   = lane >> 4;       // k-subgroup

    f32x4 acc[2][4];
    #pragma unroll
    for (int mt = 0; mt < 2; ++mt)
        #pragma unroll
        for (int nt = 0; nt < 4; ++nt)
            acc[mt][nt] = (f32x4){0.f, 0.f, 0.f, 0.f};

    for (int kc = 0; kc < 4; ++kc) {
        __syncthreads();   // h1b ready (first iter) / prev mfma reads done
        // stage W2 k-chunk transposed to bf16: thread t owns col n=t
        {
            const int n = t;
            #pragma unroll
            for (int k8 = 0; k8 < 64; k8 += 8) {
                bf16x8 v;
                #pragma unroll
                for (int j = 0; j < 8; ++j) {
                    float w = W2[(size_t)(kc * 64 + k8 + j) * H2DIM + n];
                    v[j] = (short)f2bf_rne(w);
                }
                int byte = n * 128 + k8 * 2;
                byte ^= ((n & 7) << 4);
                *(bf16x8*)(w2b + byte) = v;
            }
        }
        __syncthreads();
        #pragma unroll
        for (int ks = 0; ks < 2; ++ks) {
            const int klocal = ks * 32;
            const int kglob  = kc * 64 + klocal;
            bf16x8 afrag[2], bfrag[4];
            #pragma unroll
            for (int mt = 0; mt < 2; ++mt) {
                const int row = mt * 16 + mrow;
                int byte = row * 512 + (kglob + 8 * qk) * 2;
                byte ^= ((row & 7) << 4);
                afrag[mt] = *(const bf16x8*)(h1b + byte);
            }
            #pragma unroll
            for (int nt = 0; nt < 4; ++nt) {
                const int col = wv_ * 64 + nt * 16 + mrow;
                int byte = col * 128 + (klocal + 8 * qk) * 2;
                byte ^= ((col & 7) << 4);
                bfrag[nt] = *(const bf16x8*)(w2b + byte);
            }
            #pragma unroll
            for (int mt = 0; mt < 2; ++mt)
                #pragma unroll
                for (int nt = 0; nt < 4; ++nt)
                    acc[mt][nt] = __builtin_amdgcn_mfma_f32_16x16x32_bf16(
                        afrag[mt], bfrag[nt], acc[mt][nt], 0, 0, 0);
        }
    }

    // ---- epilogue: +b2, leaky, layer-3 partials, reduce ----
    float b2n[4];
    #pragma unroll
    for (int nt = 0; nt < 4; ++nt) b2n[nt] = b2[wv_ * 64 + nt * 16 + mrow];

    float p[8][2];
    #pragma unroll
    for (int i = 0; i < 8; ++i) { p[i][0] = 0.f; p[i][1] = 0.f; }
    #pragma unroll
    for (int mt = 0; mt < 2; ++mt)
        #pragma unroll
        for (int nt = 0; nt < 4; ++nt) {
            const int n = wv_ * 64 + nt * 16 + mrow;
            #pragma unroll
            for (int reg = 0; reg < 4; ++reg) {
                float h2v = leaky02(acc[mt][nt][reg] + b2n[nt]);
                p[mt*4 + reg][0] = fmaf(h2v, wfs[2*n + 0], p[mt*4 + reg][0]);
                p[mt*4 + reg][1] = fmaf(h2v, wfs[2*n + 1], p[mt*4 + reg][1]);
            }
        }
    // reduce over the 16 col-lanes (mrow): xor 1,2,4,8
    #pragma unroll
    for (int o = 1; o < 16; o <<= 1) {
        #pragma unroll
        for (int i = 0; i < 8; ++i) {
            p[i][0] += __shfl_xor(p[i][0], o, 64);
            p[i][1] += __shfl_xor(p[i][1], o, 64);
        }
    }
    if (mrow == 0) {
        #pragma unroll
        for (int mt = 0; mt < 2; ++mt)
            #pragma unroll
            for (int reg = 0; reg < 4; ++reg) {
                const int sample = mt * 16 + qk * 4 + reg;   // C row mapping (m89)
                oacc[wv_][sample][0] = p[mt*4 + reg][0];
                oacc[wv_][sample][1] = p[mt*4 + reg][1];
            }
    }
    __syncthreads();
    if (t < 32) {
        float o0 = bf[0], o1 = bf[1];
        #pragma unroll
        for (int w = 0; w < 4; ++w) { o0 += oacc[w][t][0]; o1 += oacc[w][t][1]; }
        float4 o4;
        o4.x = o0; o4.y = o1; o4.z = lstd[0]; o4.w = lstd[1];
        *(float4*)&out[(size_t)(blk * 32 + t) * 4] = o4;
    }
}

extern "C" void kernel_launch(void* const* d_in, const int* in_sizes, int n_in,
                              void* d_out, int out_size, void* d_ws, size_t ws_size,
                              hipStream_t stream) {
    const float* obs   = (const float*)d_in[0];
    const float* Wq    = (const float*)d_in[1];
    const float* bq    = (const float*)d_in[2];
    const float* Wk    = (const float*)d_in[3];
    const float* bk    = (const float*)d_in[4];
    const float* Wv    = (const float*)d_in[5];
    const float* bv    = (const float*)d_in[6];
    const float* v_att = (const float*)d_in[7];
    const float* temp  = (const float*)d_in[8];
    const float* ln_g  = (const float*)d_in[9];
    const float* ln_b  = (const float*)d_in[10];
    const float* W1    = (const float*)d_in[11];
    const float* b1    = (const float*)d_in[12];
    const float* W2    = (const float*)d_in[13];
    const float* b2    = (const float*)d_in[14];
    const float* Wf    = (const float*)d_in[15];
    const float* bf    = (const float*)d_in[16];
    const float* lstd  = (const float*)d_in[17];

    float* xbuf = (float*)d_ws;   // B x 22 normalized features (2.88 MB)
    float* outf = (float*)d_out;

    attn_ln_kernel<<<NBATCH / 4, 256, 0, stream>>>(
        obs, Wq, bq, Wk, bk, Wv, bv, v_att, temp, ln_g, ln_b, xbuf);
    mlp_kernel<<<NBATCH / 32, 256, 0, stream>>>(
        xbuf, W1, b1, W2, b2, Wf, bf, lstd, outf);
}

// Round 6
// 107.459 us; speedup vs baseline: 2.3579x; 1.1433x over previous
//
#include <hip/hip_runtime.h>
#include <math.h>

// Problem constants
#define NBATCH   32768
#define OWN_DIM  7
#define INTR_DIM 5
#define N_HEADS  3
#define HEAD_DIM 5
#define N_INTR   256
#define ROWLEN   1287   // OWN_DIM + N_INTR*INTR_DIM
#define XDIM     22     // OWN_DIM + N_HEADS*HEAD_DIM
#define H1DIM    256
#define H2DIM    256

typedef __attribute__((ext_vector_type(8))) short bf16x8;
typedef __attribute__((ext_vector_type(4))) float f32x4;

__device__ __forceinline__ float fast_tanh(float x) {
    // tanh(x) = 1 - 2/(exp2(2*log2e*x)+1); v_exp + v_rcp only
    float e = __builtin_amdgcn_exp2f(x * 2.885390081777927f);
    return 1.0f - 2.0f * __builtin_amdgcn_rcpf(e + 1.0f);
}

__device__ __forceinline__ float leaky02(float x) {
    return fmaxf(x, 0.2f * x);
}

__device__ __forceinline__ unsigned short f2bf_rne(float f) {
    unsigned u = __float_as_uint(f);
    return (unsigned short)((u + 0x7FFFu + ((u >> 16) & 1u)) >> 16);
}

// ---------------- Kernel A: attention + layernorm -> x (B x 22) ----------------
// one wave per sample, 4 samples per 256-thread block. NO LDS: obs row is
// read-once (no reuse), xi loaded directly from global (coalesced across
// lanes); weights read via uniform constant-offset global loads -> s_load/
// SGPR through the constant cache (scalar pipe, no VALU cost).
// __launch_bounds__(256,2): allow ~256 VGPR so xi/qb/svp stay resident
// instead of the allocator chasing the 8-wave (<=64 VGPR) occupancy step.
__global__ __launch_bounds__(256, 2) void attn_ln_kernel(
    const float* __restrict__ obs,
    const float* __restrict__ Wq, const float* __restrict__ bq,
    const float* __restrict__ Wk, const float* __restrict__ bk,
    const float* __restrict__ Wv, const float* __restrict__ bv,
    const float* __restrict__ v_att, const float* __restrict__ temp,
    const float* __restrict__ ln_g, const float* __restrict__ ln_b,
    float* __restrict__ xout)
{
    const int wid  = threadIdx.x >> 6;
    const int lane = threadIdx.x & 63;
    const int s    = blockIdx.x * 4 + wid;
    const float* row = obs + (size_t)s * ROWLEN;

    const float fac = fabsf(temp[0]) * 0.4472135954999579f;      // |T|/sqrt(5)
    const float facl2e = fac * 1.4426950408889634f;              // folded log2e

    // own[0..6]: same address across the wave (one cache line, broadcast)
    float own[OWN_DIM];
    #pragma unroll
    for (int o = 0; o < OWN_DIM; ++o) own[o] = row[o];

    // xi direct from global: items n = lane + 64*r; per r the wave covers
    // 1280 contiguous bytes -> fully coalesced dword loads
    float xi[4][INTR_DIM];
    float npf[4];                   // 0 if padded else 1
    #pragma unroll
    for (int r = 0; r < 4; ++r) {
        const float* it = row + OWN_DIM + (lane + 64*r) * INTR_DIM;
        #pragma unroll
        for (int i = 0; i < INTR_DIM; ++i) xi[r][i] = it[i];
        float asum = fabsf(xi[r][0]) + fabsf(xi[r][1]) + fabsf(xi[r][2])
                   + fabsf(xi[r][3]) + fabsf(xi[r][4]);
        npf[r] = (asum < 1e-6f) ? 0.0f : 1.0f;
    }

    float svp[N_HEADS][INTR_DIM];   // sum_n ex_n * xi_n[i]  (pre-normalized)
    float es[N_HEADS];              // sum_n ex_n

    #pragma unroll
    for (int h = 0; h < N_HEADS; ++h) {     // h compile-time constant
        // per-head weights: uniform constant-offset loads -> SGPRs
        float wk[INTR_DIM][HEAD_DIM];
        #pragma unroll
        for (int i = 0; i < INTR_DIM; ++i)
            #pragma unroll
            for (int d = 0; d < HEAD_DIM; ++d)
                wk[i][d] = Wk[h*INTR_DIM*HEAD_DIM + i*HEAD_DIM + d];
        float va[HEAD_DIM];
        #pragma unroll
        for (int d = 0; d < HEAD_DIM; ++d)
            va[d] = v_att[h*HEAD_DIM + d] * facl2e;
        // qb = q + bk
        float qb[HEAD_DIM];
        #pragma unroll
        for (int d = 0; d < HEAD_DIM; ++d) {
            float a = bq[h*HEAD_DIM + d] + bk[h*HEAD_DIM + d];
            #pragma unroll
            for (int o = 0; o < OWN_DIM; ++o)
                a = fmaf(own[o], Wq[h*OWN_DIM*HEAD_DIM + o*HEAD_DIM + d], a);
            qb[d] = a;
        }

        float sv0 = 0.f, sv1 = 0.f, sv2 = 0.f, sv3 = 0.f, sv4 = 0.f, esum = 0.f;
        #pragma unroll
        for (int r = 0; r < 4; ++r) {
            float dot = 0.0f;
            #pragma unroll
            for (int d = 0; d < HEAD_DIM; ++d) {
                float t = qb[d];
                #pragma unroll
                for (int i = 0; i < INTR_DIM; ++i)
                    t = fmaf(xi[r][i], wk[i][d], t);
                dot = fmaf(fast_tanh(t), va[d], dot);
            }
            float e = npf[r] * __builtin_amdgcn_exp2f(dot);
            esum += e;
            sv0 = fmaf(e, xi[r][0], sv0);
            sv1 = fmaf(e, xi[r][1], sv1);
            sv2 = fmaf(e, xi[r][2], sv2);
            sv3 = fmaf(e, xi[r][3], sv3);
            sv4 = fmaf(e, xi[r][4], sv4);
        }
        svp[h][0] = sv0; svp[h][1] = sv1; svp[h][2] = sv2;
        svp[h][3] = sv3; svp[h][4] = sv4; es[h] = esum;
    }

    // combined butterfly over 18 values; all lanes end with totals
    #pragma unroll
    for (int o = 1; o < 64; o <<= 1) {
        #pragma unroll
        for (int h = 0; h < N_HEADS; ++h) {
            es[h] += __shfl_xor(es[h], o, 64);
            #pragma unroll
            for (int i = 0; i < INTR_DIM; ++i)
                svp[h][i] += __shfl_xor(svp[h][i], o, 64);
        }
    }

    // normalize + deferred V projection: ctx = (svp/es) @ Wv + bv*live
    float ctx[N_HEADS][HEAD_DIM];
    #pragma unroll
    for (int h = 0; h < N_HEADS; ++h) {
        const float live = (es[h] > 0.0f) ? 1.0f : 0.0f;
        const float rinv = live * __builtin_amdgcn_rcpf(es[h]);
        float svn[INTR_DIM];
        #pragma unroll
        for (int i = 0; i < INTR_DIM; ++i) svn[i] = svp[h][i] * rinv;
        #pragma unroll
        for (int d = 0; d < HEAD_DIM; ++d) {
            float c = bv[h*HEAD_DIM + d] * live;
            #pragma unroll
            for (int i = 0; i < INTR_DIM; ++i)
                c = fmaf(svn[i], Wv[h*INTR_DIM*HEAD_DIM + i*HEAD_DIM + d], c);
            ctx[h][d] = c;
        }
    }

    // layernorm over x = [own(7), ctx(15)] computed redundantly per lane
    float sum = 0.0f;
    #pragma unroll
    for (int o = 0; o < OWN_DIM; ++o) sum += own[o];
    #pragma unroll
    for (int h = 0; h < N_HEADS; ++h)
        #pragma unroll
        for (int d = 0; d < HEAD_DIM; ++d) sum += ctx[h][d];
    const float mu = sum * (1.0f / 22.0f);
    float var = 0.0f;
    #pragma unroll
    for (int o = 0; o < OWN_DIM; ++o) { float dd = own[o] - mu; var += dd*dd; }
    #pragma unroll
    for (int h = 0; h < N_HEADS; ++h)
        #pragma unroll
        for (int d = 0; d < HEAD_DIM; ++d) { float dd = ctx[h][d] - mu; var += dd*dd; }
    var *= (1.0f / 22.0f);
    const float rs = rsqrtf(var + 1e-5f);

    // lane j < 22 writes element j (static cndmask select chain, coalesced store)
    float xv = own[0];
    #pragma unroll
    for (int o = 1; o < OWN_DIM; ++o) xv = (lane == o) ? own[o] : xv;
    #pragma unroll
    for (int j = 0; j < 15; ++j) xv = (lane == OWN_DIM + j) ? ctx[j/5][j%5] : xv;
    if (lane < XDIM) {
        xout[(size_t)s * XDIM + lane] = (xv - mu) * rs * ln_g[lane] + ln_b[lane];
    }
}

// ---------------- Kernel B: MLP 22->256->256->2 (+log_std) ----------------
// (unchanged — 4.4 us, MFMA layer-2, verified round 5)
__global__ __launch_bounds__(256) void mlp_kernel(
    const float* __restrict__ x,
    const float* __restrict__ W1, const float* __restrict__ b1,
    const float* __restrict__ W2, const float* __restrict__ b2,
    const float* __restrict__ Wf, const float* __restrict__ bf,
    const float* __restrict__ lstd, float* __restrict__ out)
{
    __shared__ __align__(16) float xs[32 * XDIM];              //  2.8 KB
    __shared__ __align__(16) unsigned char h1b[32 * 256 * 2];  // 16 KB bf16 [m][k]
    __shared__ __align__(16) unsigned char w2b[256 * 64 * 2];  // 32 KB bf16 [n][kchunk]
    __shared__ __align__(16) float wfs[H2DIM * 2];             //  2 KB
    __shared__ float oacc[4][32][2];                           //  1 KB

    const int t   = threadIdx.x;
    const int blk = blockIdx.x;

    for (int i = t; i < 32 * XDIM; i += 256) xs[i] = x[(size_t)blk * 32 * XDIM + i];
    for (int i = t; i < H2DIM * 2; i += 256) wfs[i] = Wf[i];

    // ---- layer 1: thread t computes h1[:, t] -> bf16 LDS column ----
    float w1r[XDIM];
    #pragma unroll
    for (int i = 0; i < XDIM; ++i) w1r[i] = W1[i * H1DIM + t];
    const float b1t = b1[t];
    __syncthreads();
    for (int e = 0; e < 32; ++e) {
        float a = b1t;
        #pragma unroll
        for (int i = 0; i < XDIM; ++i) a += xs[e * XDIM + i] * w1r[i];
        a = leaky02(a);
        int byte = e * 512 + t * 2;
        byte ^= ((e & 7) << 4);
        *(unsigned short*)(h1b + byte) = f2bf_rne(a);
    }

    // ---- layer 2: C[32][256] = h1 @ W2 via MFMA; wave owns 64-col slab ----
    const int wv_  = t >> 6;
    const int lane = t & 63;
    const int mrow = lane & 15;
    const int qk   = lane >> 4;

    f32x4 acc[2][4];
    #pragma unroll
    for (int mt = 0; mt < 2; ++mt)
        #pragma unroll
        for (int nt = 0; nt < 4; ++nt)
            acc[mt][nt] = (f32x4){0.f, 0.f, 0.f, 0.f};

    for (int kc = 0; kc < 4; ++kc) {
        __syncthreads();
        {
            const int n = t;
            #pragma unroll
            for (int k8 = 0; k8 < 64; k8 += 8) {
                bf16x8 v;
                #pragma unroll
                for (int j = 0; j < 8; ++j) {
                    float w = W2[(size_t)(kc * 64 + k8 + j) * H2DIM + n];
                    v[j] = (short)f2bf_rne(w);
                }
                int byte = n * 128 + k8 * 2;
                byte ^= ((n & 7) << 4);
                *(bf16x8*)(w2b + byte) = v;
            }
        }
        __syncthreads();
        #pragma unroll
        for (int ks = 0; ks < 2; ++ks) {
            const int klocal = ks * 32;
            const int kglob  = kc * 64 + klocal;
            bf16x8 afrag[2], bfrag[4];
            #pragma unroll
            for (int mt = 0; mt < 2; ++mt) {
                const int rowi = mt * 16 + mrow;
                int byte = rowi * 512 + (kglob + 8 * qk) * 2;
                byte ^= ((rowi & 7) << 4);
                afrag[mt] = *(const bf16x8*)(h1b + byte);
            }
            #pragma unroll
            for (int nt = 0; nt < 4; ++nt) {
                const int col = wv_ * 64 + nt * 16 + mrow;
                int byte = col * 128 + (klocal + 8 * qk) * 2;
                byte ^= ((col & 7) << 4);
                bfrag[nt] = *(const bf16x8*)(w2b + byte);
            }
            #pragma unroll
            for (int mt = 0; mt < 2; ++mt)
                #pragma unroll
                for (int nt = 0; nt < 4; ++nt)
                    acc[mt][nt] = __builtin_amdgcn_mfma_f32_16x16x32_bf16(
                        afrag[mt], bfrag[nt], acc[mt][nt], 0, 0, 0);
        }
    }

    // ---- epilogue: +b2, leaky, layer-3 partials, reduce ----
    float b2n[4];
    #pragma unroll
    for (int nt = 0; nt < 4; ++nt) b2n[nt] = b2[wv_ * 64 + nt * 16 + mrow];

    float p[8][2];
    #pragma unroll
    for (int i = 0; i < 8; ++i) { p[i][0] = 0.f; p[i][1] = 0.f; }
    #pragma unroll
    for (int mt = 0; mt < 2; ++mt)
        #pragma unroll
        for (int nt = 0; nt < 4; ++nt) {
            const int n = wv_ * 64 + nt * 16 + mrow;
            #pragma unroll
            for (int reg = 0; reg < 4; ++reg) {
                float h2v = leaky02(acc[mt][nt][reg] + b2n[nt]);
                p[mt*4 + reg][0] = fmaf(h2v, wfs[2*n + 0], p[mt*4 + reg][0]);
                p[mt*4 + reg][1] = fmaf(h2v, wfs[2*n + 1], p[mt*4 + reg][1]);
            }
        }
    #pragma unroll
    for (int o = 1; o < 16; o <<= 1) {
        #pragma unroll
        for (int i = 0; i < 8; ++i) {
            p[i][0] += __shfl_xor(p[i][0], o, 64);
            p[i][1] += __shfl_xor(p[i][1], o, 64);
        }
    }
    if (mrow == 0) {
        #pragma unroll
        for (int mt = 0; mt < 2; ++mt)
            #pragma unroll
            for (int reg = 0; reg < 4; ++reg) {
                const int sample = mt * 16 + qk * 4 + reg;   // C row mapping (m89)
                oacc[wv_][sample][0] = p[mt*4 + reg][0];
                oacc[wv_][sample][1] = p[mt*4 + reg][1];
            }
    }
    __syncthreads();
    if (t < 32) {
        float o0 = bf[0], o1 = bf[1];
        #pragma unroll
        for (int w = 0; w < 4; ++w) { o0 += oacc[w][t][0]; o1 += oacc[w][t][1]; }
        float4 o4;
        o4.x = o0; o4.y = o1; o4.z = lstd[0]; o4.w = lstd[1];
        *(float4*)&out[(size_t)(blk * 32 + t) * 4] = o4;
    }
}

extern "C" void kernel_launch(void* const* d_in, const int* in_sizes, int n_in,
                              void* d_out, int out_size, void* d_ws, size_t ws_size,
                              hipStream_t stream) {
    const float* obs   = (const float*)d_in[0];
    const float* Wq    = (const float*)d_in[1];
    const float* bq    = (const float*)d_in[2];
    const float* Wk    = (const float*)d_in[3];
    const float* bk    = (const float*)d_in[4];
    const float* Wv    = (const float*)d_in[5];
    const float* bv    = (const float*)d_in[6];
    const float* v_att = (const float*)d_in[7];
    const float* temp  = (const float*)d_in[8];
    const float* ln_g  = (const float*)d_in[9];
    const float* ln_b  = (const float*)d_in[10];
    const float* W1    = (const float*)d_in[11];
    const float* b1    = (const float*)d_in[12];
    const float* W2    = (const float*)d_in[13];
    const float* b2    = (const float*)d_in[14];
    const float* Wf    = (const float*)d_in[15];
    const float* bf    = (const float*)d_in[16];
    const float* lstd  = (const float*)d_in[17];

    float* xbuf = (float*)d_ws;   // B x 22 normalized features (2.88 MB)
    float* outf = (float*)d_out;

    attn_ln_kernel<<<NBATCH / 4, 256, 0, stream>>>(
        obs, Wq, bq, Wk, bk, Wv, bv, v_att, temp, ln_g, ln_b, xbuf);
    mlp_kernel<<<NBATCH / 32, 256, 0, stream>>>(
        xbuf, W1, b1, W2, b2, Wf, bf, lstd, outf);
}

// Round 7
// 91.361 us; speedup vs baseline: 2.7734x; 1.1762x over previous
//
#include <hip/hip_runtime.h>
#include <math.h>

// Problem constants
#define NBATCH   32768
#define OWN_DIM  7
#define INTR_DIM 5
#define N_HEADS  3
#define HEAD_DIM 5
#define N_INTR   256
#define ROWLEN   1287   // OWN_DIM + N_INTR*INTR_DIM
#define XDIM     22     // OWN_DIM + N_HEADS*HEAD_DIM
#define H1DIM    256
#define H2DIM    256

typedef __attribute__((ext_vector_type(8))) short bf16x8;
typedef __attribute__((ext_vector_type(4))) float f32x4;

__device__ __forceinline__ float leaky02(float x) {
    return fmaxf(x, 0.2f * x);
}

__device__ __forceinline__ unsigned short f2bf_rne(float f) {
    unsigned u = __float_as_uint(f);
    return (unsigned short)((u + 0x7FFFu + ((u >> 16) & 1u)) >> 16);
}

// ---------------- Kernel A: attention + layernorm -> x (B x 22) ----------------
// FOUR samples per wave (16 lanes each), 16 samples per 256-thread block.
// Rationale (r6 counters): per-wave overhead (q-proj, 18-value butterfly, LN,
// epilogue) replicated 32x/SIMD at 1 sample/wave was ~19 us of redundancy.
// At 4 samples/wave the same per-wave op count serves 4 samples and the
// butterfly shrinks to 4 levels within 16-lane groups.
// tanh folded algebraically: sum_d va*tanh = sum_d va - 2*sum_d va*rcp(e+1).
__global__ __launch_bounds__(256, 2) void attn_ln_kernel(
    const float* __restrict__ obs,
    const float* __restrict__ Wq, const float* __restrict__ bq,
    const float* __restrict__ Wk, const float* __restrict__ bk,
    const float* __restrict__ Wv, const float* __restrict__ bv,
    const float* __restrict__ v_att, const float* __restrict__ temp,
    const float* __restrict__ ln_g, const float* __restrict__ ln_b,
    float* __restrict__ xout)
{
    const int wid  = threadIdx.x >> 6;
    const int lane = threadIdx.x & 63;
    const int grp  = lane >> 4;     // sample slot within wave (0..3)
    const int gl   = lane & 15;     // lane within 16-lane sample group
    const int s    = blockIdx.x * 16 + wid * 4 + grp;
    const float* row = obs + (size_t)s * ROWLEN;

    const float fac = fabsf(temp[0]) * 0.4472135954999579f;      // |T|/sqrt(5)
    const float facl2e = fac * 1.4426950408889634f;              // * log2e
    const float TL2E = 2.885390081777927f;                       // 2*log2e

    // own[0..6] of this lane's sample (16-way broadcast per group)
    float own[OWN_DIM];
    #pragma unroll
    for (int o = 0; o < OWN_DIM; ++o) own[o] = row[o];

    // per-head score constants: va2 = -2*facl2e*v_att, vasum = facl2e*sum(v_att)
    float va2[N_HEADS][HEAD_DIM], vasum[N_HEADS];
    #pragma unroll
    for (int h = 0; h < N_HEADS; ++h) {
        float ssum = 0.0f;
        #pragma unroll
        for (int d = 0; d < HEAD_DIM; ++d) {
            float v = v_att[h*HEAD_DIM + d];
            ssum += v;
            va2[h][d] = v * (-2.0f * facl2e);
        }
        vasum[h] = ssum * facl2e;
    }

    // qb[h][d] = q + bk for this lane's sample
    float qb[N_HEADS][HEAD_DIM];
    #pragma unroll
    for (int h = 0; h < N_HEADS; ++h)
        #pragma unroll
        for (int d = 0; d < HEAD_DIM; ++d) {
            float a = bq[h*HEAD_DIM + d] + bk[h*HEAD_DIM + d];
            #pragma unroll
            for (int o = 0; o < OWN_DIM; ++o)
                a = fmaf(own[o], Wq[h*OWN_DIM*HEAD_DIM + o*HEAD_DIM + d], a);
            qb[h][d] = a;
        }

    // accumulators: svp[h][i] = sum_n e_n*xi_n[i], es[h] = sum_n e_n
    float svp[N_HEADS][INTR_DIM] = {};
    float es[N_HEADS] = {};

    // 16 items per lane: n = gl + 16*r (group reads 320B contiguous per r)
    #pragma unroll
    for (int r = 0; r < 16; ++r) {
        const float* it = row + OWN_DIM + (gl + 16*r) * INTR_DIM;
        float xi[INTR_DIM];
        #pragma unroll
        for (int i = 0; i < INTR_DIM; ++i) xi[i] = it[i];
        float asum = fabsf(xi[0]) + fabsf(xi[1]) + fabsf(xi[2])
                   + fabsf(xi[3]) + fabsf(xi[4]);
        const float npf = (asum < 1e-6f) ? 0.0f : 1.0f;
        #pragma unroll
        for (int h = 0; h < N_HEADS; ++h) {
            float dot = vasum[h];
            #pragma unroll
            for (int d = 0; d < HEAD_DIM; ++d) {
                float t = qb[h][d];
                #pragma unroll
                for (int i = 0; i < INTR_DIM; ++i)
                    t = fmaf(xi[i], Wk[h*INTR_DIM*HEAD_DIM + i*HEAD_DIM + d], t);
                float e = __builtin_amdgcn_exp2f(t * TL2E);
                float rc = __builtin_amdgcn_rcpf(e + 1.0f);
                dot = fmaf(va2[h][d], rc, dot);     // == facl2e*sum va*tanh
            }
            float e = npf * __builtin_amdgcn_exp2f(dot);
            es[h] += e;
            #pragma unroll
            for (int i = 0; i < INTR_DIM; ++i)
                svp[h][i] = fmaf(e, xi[i], svp[h][i]);
        }
    }

    // 4-level butterfly within each 16-lane group (18 values)
    #pragma unroll
    for (int o = 1; o < 16; o <<= 1) {
        #pragma unroll
        for (int h = 0; h < N_HEADS; ++h) {
            es[h] += __shfl_xor(es[h], o, 64);
            #pragma unroll
            for (int i = 0; i < INTR_DIM; ++i)
                svp[h][i] += __shfl_xor(svp[h][i], o, 64);
        }
    }

    // normalize + deferred V projection: ctx = (svp/es) @ Wv + bv*live
    float ctx[N_HEADS][HEAD_DIM];
    #pragma unroll
    for (int h = 0; h < N_HEADS; ++h) {
        const float live = (es[h] > 0.0f) ? 1.0f : 0.0f;
        const float rinv = live * __builtin_amdgcn_rcpf(es[h]);
        float svn[INTR_DIM];
        #pragma unroll
        for (int i = 0; i < INTR_DIM; ++i) svn[i] = svp[h][i] * rinv;
        #pragma unroll
        for (int d = 0; d < HEAD_DIM; ++d) {
            float c = bv[h*HEAD_DIM + d] * live;
            #pragma unroll
            for (int i = 0; i < INTR_DIM; ++i)
                c = fmaf(svn[i], Wv[h*INTR_DIM*HEAD_DIM + i*HEAD_DIM + d], c);
            ctx[h][d] = c;
        }
    }

    // layernorm over x = [own(7), ctx(15)] (redundant across the 16 group lanes)
    float sum = 0.0f;
    #pragma unroll
    for (int o = 0; o < OWN_DIM; ++o) sum += own[o];
    #pragma unroll
    for (int h = 0; h < N_HEADS; ++h)
        #pragma unroll
        for (int d = 0; d < HEAD_DIM; ++d) sum += ctx[h][d];
    const float mu = sum * (1.0f / 22.0f);
    float var = 0.0f;
    #pragma unroll
    for (int o = 0; o < OWN_DIM; ++o) { float dd = own[o] - mu; var += dd*dd; }
    #pragma unroll
    for (int h = 0; h < N_HEADS; ++h)
        #pragma unroll
        for (int d = 0; d < HEAD_DIM; ++d) { float dd = ctx[h][d] - mu; var += dd*dd; }
    var *= (1.0f / 22.0f);
    const float rs = rsqrtf(var + 1e-5f);

    // lane gl writes elements gl and gl+16 (if <22) via static select chains
    float xv0 = own[0];
    #pragma unroll
    for (int o = 1; o < OWN_DIM; ++o) xv0 = (gl == o) ? own[o] : xv0;
    #pragma unroll
    for (int j = 0; j < 15; ++j) xv0 = (gl == OWN_DIM + j) ? ctx[j/5][j%5] : xv0;
    float xv1 = ctx[1][4];                    // element 16 -> ctx j=9
    #pragma unroll
    for (int j = 10; j < 15; ++j) xv1 = (gl == j - 9) ? ctx[j/5][j%5] : xv1;

    float* xo = xout + (size_t)s * XDIM;
    xo[gl] = (xv0 - mu) * rs * ln_g[gl] + ln_b[gl];
    if (gl < XDIM - 16) {
        xo[16 + gl] = (xv1 - mu) * rs * ln_g[16 + gl] + ln_b[16 + gl];
    }
}

// ---------------- Kernel B: MLP 22->256->256->2 (+log_std) ----------------
// (unchanged — 4.4 us, MFMA layer-2, verified round 5)
__global__ __launch_bounds__(256) void mlp_kernel(
    const float* __restrict__ x,
    const float* __restrict__ W1, const float* __restrict__ b1,
    const float* __restrict__ W2, const float* __restrict__ b2,
    const float* __restrict__ Wf, const float* __restrict__ bf,
    const float* __restrict__ lstd, float* __restrict__ out)
{
    __shared__ __align__(16) float xs[32 * XDIM];              //  2.8 KB
    __shared__ __align__(16) unsigned char h1b[32 * 256 * 2];  // 16 KB bf16 [m][k]
    __shared__ __align__(16) unsigned char w2b[256 * 64 * 2];  // 32 KB bf16 [n][kchunk]
    __shared__ __align__(16) float wfs[H2DIM * 2];             //  2 KB
    __shared__ float oacc[4][32][2];                           //  1 KB

    const int t   = threadIdx.x;
    const int blk = blockIdx.x;

    for (int i = t; i < 32 * XDIM; i += 256) xs[i] = x[(size_t)blk * 32 * XDIM + i];
    for (int i = t; i < H2DIM * 2; i += 256) wfs[i] = Wf[i];

    // ---- layer 1: thread t computes h1[:, t] -> bf16 LDS column ----
    float w1r[XDIM];
    #pragma unroll
    for (int i = 0; i < XDIM; ++i) w1r[i] = W1[i * H1DIM + t];
    const float b1t = b1[t];
    __syncthreads();
    for (int e = 0; e < 32; ++e) {
        float a = b1t;
        #pragma unroll
        for (int i = 0; i < XDIM; ++i) a += xs[e * XDIM + i] * w1r[i];
        a = leaky02(a);
        int byte = e * 512 + t * 2;
        byte ^= ((e & 7) << 4);
        *(unsigned short*)(h1b + byte) = f2bf_rne(a);
    }

    // ---- layer 2: C[32][256] = h1 @ W2 via MFMA; wave owns 64-col slab ----
    const int wv_  = t >> 6;
    const int lane = t & 63;
    const int mrow = lane & 15;
    const int qk   = lane >> 4;

    f32x4 acc[2][4];
    #pragma unroll
    for (int mt = 0; mt < 2; ++mt)
        #pragma unroll
        for (int nt = 0; nt < 4; ++nt)
            acc[mt][nt] = (f32x4){0.f, 0.f, 0.f, 0.f};

    for (int kc = 0; kc < 4; ++kc) {
        __syncthreads();
        {
            const int n = t;
            #pragma unroll
            for (int k8 = 0; k8 < 64; k8 += 8) {
                bf16x8 v;
                #pragma unroll
                for (int j = 0; j < 8; ++j) {
                    float w = W2[(size_t)(kc * 64 + k8 + j) * H2DIM + n];
                    v[j] = (short)f2bf_rne(w);
                }
                int byte = n * 128 + k8 * 2;
                byte ^= ((n & 7) << 4);
                *(bf16x8*)(w2b + byte) = v;
            }
        }
        __syncthreads();
        #pragma unroll
        for (int ks = 0; ks < 2; ++ks) {
            const int klocal = ks * 32;
            const int kglob  = kc * 64 + klocal;
            bf16x8 afrag[2], bfrag[4];
            #pragma unroll
            for (int mt = 0; mt < 2; ++mt) {
                const int rowi = mt * 16 + mrow;
                int byte = rowi * 512 + (kglob + 8 * qk) * 2;
                byte ^= ((rowi & 7) << 4);
                afrag[mt] = *(const bf16x8*)(h1b + byte);
            }
            #pragma unroll
            for (int nt = 0; nt < 4; ++nt) {
                const int col = wv_ * 64 + nt * 16 + mrow;
                int byte = col * 128 + (klocal + 8 * qk) * 2;
                byte ^= ((col & 7) << 4);
                bfrag[nt] = *(const bf16x8*)(w2b + byte);
            }
            #pragma unroll
            for (int mt = 0; mt < 2; ++mt)
                #pragma unroll
                for (int nt = 0; nt < 4; ++nt)
                    acc[mt][nt] = __builtin_amdgcn_mfma_f32_16x16x32_bf16(
                        afrag[mt], bfrag[nt], acc[mt][nt], 0, 0, 0);
        }
    }

    // ---- epilogue: +b2, leaky, layer-3 partials, reduce ----
    float b2n[4];
    #pragma unroll
    for (int nt = 0; nt < 4; ++nt) b2n[nt] = b2[wv_ * 64 + nt * 16 + mrow];

    float p[8][2];
    #pragma unroll
    for (int i = 0; i < 8; ++i) { p[i][0] = 0.f; p[i][1] = 0.f; }
    #pragma unroll
    for (int mt = 0; mt < 2; ++mt)
        #pragma unroll
        for (int nt = 0; nt < 4; ++nt) {
            const int n = wv_ * 64 + nt * 16 + mrow;
            #pragma unroll
            for (int reg = 0; reg < 4; ++reg) {
                float h2v = leaky02(acc[mt][nt][reg] + b2n[nt]);
                p[mt*4 + reg][0] = fmaf(h2v, wfs[2*n + 0], p[mt*4 + reg][0]);
                p[mt*4 + reg][1] = fmaf(h2v, wfs[2*n + 1], p[mt*4 + reg][1]);
            }
        }
    #pragma unroll
    for (int o = 1; o < 16; o <<= 1) {
        #pragma unroll
        for (int i = 0; i < 8; ++i) {
            p[i][0] += __shfl_xor(p[i][0], o, 64);
            p[i][1] += __shfl_xor(p[i][1], o, 64);
        }
    }
    if (mrow == 0) {
        #pragma unroll
        for (int mt = 0; mt < 2; ++mt)
            #pragma unroll
            for (int reg = 0; reg < 4; ++reg) {
                const int sample = mt * 16 + qk * 4 + reg;   // C row mapping (m89)
                oacc[wv_][sample][0] = p[mt*4 + reg][0];
                oacc[wv_][sample][1] = p[mt*4 + reg][1];
            }
    }
    __syncthreads();
    if (t < 32) {
        float o0 = bf[0], o1 = bf[1];
        #pragma unroll
        for (int w = 0; w < 4; ++w) { o0 += oacc[w][t][0]; o1 += oacc[w][t][1]; }
        float4 o4;
        o4.x = o0; o4.y = o1; o4.z = lstd[0]; o4.w = lstd[1];
        *(float4*)&out[(size_t)(blk * 32 + t) * 4] = o4;
    }
}

extern "C" void kernel_launch(void* const* d_in, const int* in_sizes, int n_in,
                              void* d_out, int out_size, void* d_ws, size_t ws_size,
                              hipStream_t stream) {
    const float* obs   = (const float*)d_in[0];
    const float* Wq    = (const float*)d_in[1];
    const float* bq    = (const float*)d_in[2];
    const float* Wk    = (const float*)d_in[3];
    const float* bk    = (const float*)d_in[4];
    const float* Wv    = (const float*)d_in[5];
    const float* bv    = (const float*)d_in[6];
    const float* v_att = (const float*)d_in[7];
    const float* temp  = (const float*)d_in[8];
    const float* ln_g  = (const float*)d_in[9];
    const float* ln_b  = (const float*)d_in[10];
    const float* W1    = (const float*)d_in[11];
    const float* b1    = (const float*)d_in[12];
    const float* W2    = (const float*)d_in[13];
    const float* b2    = (const float*)d_in[14];
    const float* Wf    = (const float*)d_in[15];
    const float* bf    = (const float*)d_in[16];
    const float* lstd  = (const float*)d_in[17];

    float* xbuf = (float*)d_ws;   // B x 22 normalized features (2.88 MB)
    float* outf = (float*)d_out;

    attn_ln_kernel<<<NBATCH / 16, 256, 0, stream>>>(
        obs, Wq, bq, Wk, bk, Wv, bv, v_att, temp, ln_g, ln_b, xbuf);
    mlp_kernel<<<NBATCH / 32, 256, 0, stream>>>(
        xbuf, W1, b1, W2, b2, Wf, bf, lstd, outf);
}